// Round 5
// baseline (5004.900 us; speedup 1.0000x reference)
//
#include <hip/hip_runtime.h>
#include <hip/hip_bf16.h>

// RQV residual vector-quantization — MFMA fp16-split design.
// Inputs (fp32): data [16,256,2048], codebooks [8,1024,256], N_i [8,1024], m_i [8,1024,256]
// Outputs (fp32 concat): logits [16,256,2048], loss [1], indices [8,16,2048],
//   new_N [8,1024], new_m [8,1024,256], new_W [8,1024,256]
// ws: Whl frag buffer 8.39MB + fp32 scratch 8.45MB = 16.85MB.

using f16   = _Float16;
using f16x8 = __attribute__((ext_vector_type(8))) _Float16;
using f32x4 = __attribute__((ext_vector_type(4))) float;

#define GAMMA_F 0.99f
#define OMG_F   0.01f
#define LO_SCALE 1024.0f
#define LO_INV   (1.0f/1024.0f)

__global__ void sentinel_kernel(float* out, float v){
  if (threadIdx.x == 0 && blockIdx.x == 0) out[0] = v;
}

// ---------- row sum-of-squares (cols = 256), one wave per row ----------
__global__ __launch_bounds__(64) void rownorm_kernel(const float* __restrict__ X,
                                                     float* __restrict__ out, int rows){
  int r = blockIdx.x;
  if (r >= rows) return;
  int l = threadIdx.x;
  const float* x = X + (size_t)r * 256;
  float s = 0.f;
  #pragma unroll
  for (int i = 0; i < 4; i++){ float v = x[l + i*64]; s += v*v; }
  #pragma unroll
  for (int o = 32; o > 0; o >>= 1) s += __shfl_down(s, o, 64);
  if (l == 0) out[r] = s;
}

// ---------- codebook split into MFMA B-fragment order ----------
// frag[(q*64+ct)*8+kf] is 1024 halfs: [hl][lane][i] with
// B[k = kf*32+(lane>>4)*8+i][col = ct*16+(lane&15)] = W[q][col][k].
__global__ __launch_bounds__(64) void wsplit_kernel(const float* __restrict__ W,
                                                    f16* __restrict__ frag){
  int blk = blockIdx.x;                 // 0..4095 = (q*64+ct)*8+kf
  int kf = blk & 7, ct = (blk >> 3) & 63, q = blk >> 9;
  int lane = threadIdx.x;
  int code = q*1024 + ct*16 + (lane & 15);
  int k0   = kf*32 + (lane >> 4)*8;
  const float* src = W + (size_t)code * 256 + k0;
  float4 a = *(const float4*)(src);
  float4 b = *(const float4*)(src + 4);
  float x[8] = {a.x,a.y,a.z,a.w, b.x,b.y,b.z,b.w};
  f16x8 h8, l8;
  #pragma unroll
  for (int i = 0; i < 8; i++){
    f16 h = (f16)x[i];
    h8[i] = h;
    l8[i] = (f16)((x[i] - (float)h) * LO_SCALE);
  }
  f16* dst = frag + (size_t)blk * 1024 + lane*8;
  *(f16x8*)dst         = h8;
  *(f16x8*)(dst + 512) = l8;
}

// ---------- fused RVQ: 32 rows/block, resid as fp16 hi/lo in LDS ----------
// LDS: rsh/rsl [32][264] halfs (33.8KB) + reduction buffers (~1.5KB).
__global__ __launch_bounds__(256, 3) void rvq_kernel(
    const float* __restrict__ data, const float* __restrict__ codebooks,
    const f16* __restrict__ frag, const float* __restrict__ wnorm_all,
    float* __restrict__ counts, float* __restrict__ vec, float* __restrict__ loss_acc,
    float* __restrict__ out0, float* __restrict__ out2)
{
  __shared__ f16 rsh[32][264];
  __shared__ f16 rsl[32][264];
  __shared__ float red_v[4][32];
  __shared__ int   red_i[4][32];
  __shared__ float rn_s[32];
  __shared__ int   code_s[32];

  const int blk  = blockIdx.x;          // 0..1023
  const int b    = blk >> 6;
  const int s0   = (blk & 63) * 32;
  const int tid  = threadIdx.x;
  const int lane = tid & 63;
  const int wave = tid >> 6;
  const float* dptr = data + (size_t)b * 524288 + s0;   // [d][s] slab

  // transpose-in + fp16 split: rsh/rsl[row=s_local][k=d]
  {
    int c = tid & 31, g = tid >> 5;     // g 0..7
    #pragma unroll
    for (int dc = 0; dc < 4; ++dc){
      int d0 = g*32 + dc*8;
      f16x8 h8, l8;
      #pragma unroll
      for (int j = 0; j < 8; ++j){
        float x = dptr[(size_t)(d0+j)*2048 + c];
        f16 h = (f16)x;
        h8[j] = h;
        l8[j] = (f16)((x - (float)h) * LO_SCALE);
      }
      *(f16x8*)&rsh[c][d0] = h8;
      *(f16x8*)&rsl[c][d0] = l8;
    }
  }
  __syncthreads();
  // initial per-row ||r||^2
  {
    int row = tid >> 3, j0 = (tid & 7) * 32;
    float s = 0.f;
    #pragma unroll
    for (int jc = 0; jc < 4; ++jc){
      f16x8 h8 = *(const f16x8*)&rsh[row][j0 + jc*8];
      f16x8 l8 = *(const f16x8*)&rsl[row][j0 + jc*8];
      #pragma unroll
      for (int j = 0; j < 8; ++j){
        float v = (float)h8[j] + (float)l8[j] * LO_INV;
        s += v*v;
      }
    }
    s += __shfl_down(s, 4, 8); s += __shfl_down(s, 2, 8); s += __shfl_down(s, 1, 8);
    if ((tid & 7) == 0) rn_s[row] = s;
  }
  __syncthreads();

  const int rlo = lane & 15;   // code-col within tile / row within A-tile
  const int kg  = lane >> 4;   // k-subgroup

  for (int q = 0; q < 8; ++q){
    const float* wn = wnorm_all + (q << 10);
    float bestv[8]; int besti[8];
    #pragma unroll
    for (int r = 0; r < 8; ++r){ bestv[r] = 3.4e38f; besti[r] = 0; }

    for (int ctb = 0; ctb < 4; ++ctb){
      f32x4 ahh[4][2], acr[4][2];
      #pragma unroll
      for (int c = 0; c < 4; ++c)
        #pragma unroll
        for (int rt = 0; rt < 2; ++rt){ ahh[c][rt] = (f32x4)0.0f; acr[c][rt] = (f32x4)0.0f; }

      for (int kf = 0; kf < 8; ++kf){
        int k0 = kf*32 + kg*8;
        f16x8 a0h = *(const f16x8*)&rsh[rlo][k0];
        f16x8 a1h = *(const f16x8*)&rsh[16 + rlo][k0];
        f16x8 a0l = *(const f16x8*)&rsl[rlo][k0];
        f16x8 a1l = *(const f16x8*)&rsl[16 + rlo][k0];
        #pragma unroll
        for (int c = 0; c < 4; ++c){
          int ct = (wave << 4) + (ctb << 2) + c;              // 0..63
          const f16x8* fp = (const f16x8*)(frag + ((((size_t)q*64 + ct)*8 + kf) << 10));
          f16x8 bh = fp[lane];
          f16x8 bl = fp[64 + lane];
          ahh[c][0] = __builtin_amdgcn_mfma_f32_16x16x32_f16(a0h, bh, ahh[c][0], 0,0,0);
          acr[c][0] = __builtin_amdgcn_mfma_f32_16x16x32_f16(a0h, bl, acr[c][0], 0,0,0);
          acr[c][0] = __builtin_amdgcn_mfma_f32_16x16x32_f16(a0l, bh, acr[c][0], 0,0,0);
          ahh[c][1] = __builtin_amdgcn_mfma_f32_16x16x32_f16(a1h, bh, ahh[c][1], 0,0,0);
          acr[c][1] = __builtin_amdgcn_mfma_f32_16x16x32_f16(a1h, bl, acr[c][1], 0,0,0);
          acr[c][1] = __builtin_amdgcn_mfma_f32_16x16x32_f16(a1l, bh, acr[c][1], 0,0,0);
        }
      }
      // fold wnorm+rownorm, per-lane argmin (codes ascend with ctb,c)
      #pragma unroll
      for (int c = 0; c < 4; ++c){
        int code = (((wave << 4) + (ctb << 2) + c) << 4) + rlo;
        float wnc = wn[code];
        #pragma unroll
        for (int rt = 0; rt < 2; ++rt){
          #pragma unroll
          for (int i = 0; i < 4; ++i){
            int row = rt*16 + kg*4 + i;
            float dot = ahh[c][rt][i] + acr[c][rt][i] * LO_INV;
            float d2 = (rn_s[row] + wnc) - 2.0f * dot;
            int r8 = rt*4 + i;
            if (d2 < bestv[r8] || (d2 == bestv[r8] && code < besti[r8])){
              bestv[r8] = d2; besti[r8] = code;
            }
          }
        }
      }
    }
    // reduce over the 16 code-lanes (first-min, lowest index on ties)
    #pragma unroll
    for (int off = 1; off <= 8; off <<= 1){
      #pragma unroll
      for (int r8 = 0; r8 < 8; ++r8){
        float ov = __shfl_xor(bestv[r8], off, 16);
        int   oi = __shfl_xor(besti[r8], off, 16);
        if (ov < bestv[r8] || (ov == bestv[r8] && oi < besti[r8])){
          bestv[r8] = ov; besti[r8] = oi;
        }
      }
    }
    if (rlo == 0){
      #pragma unroll
      for (int r8 = 0; r8 < 8; ++r8){
        int row = (r8 >> 2)*16 + kg*4 + (r8 & 3);
        red_v[wave][row] = bestv[r8];
        red_i[wave][row] = besti[r8];
      }
    }
    __syncthreads();
    if (tid < 32){
      float bv = red_v[0][tid]; int bi = red_i[0][tid];
      #pragma unroll
      for (int w = 1; w < 4; ++w){
        float v = red_v[w][tid]; int ii = red_i[w][tid];
        if (v < bv || (v == bv && ii < bi)){ bv = v; bi = ii; }
      }
      code_s[tid] = bi;
      out2[(size_t)q*32768 + (size_t)b*2048 + s0 + tid] = (float)bi;
      atomicAdd(&counts[(q << 10) + bi], 1.0f);
    }
    __syncthreads();
    // update: vec[code] += stage-input resid; resid -= W[code]; next rownorm
    {
      int row = tid >> 3, j0 = (tid & 7) * 32;
      int code = code_s[row];
      const float* wrow = codebooks + ((size_t)q*1024 + code)*256 + j0;
      float* vrow = vec + ((size_t)q*1024 + code)*256 + j0;
      float s = 0.f;
      #pragma unroll
      for (int jc = 0; jc < 4; ++jc){
        f16x8 h8 = *(const f16x8*)&rsh[row][j0 + jc*8];
        f16x8 l8 = *(const f16x8*)&rsl[row][j0 + jc*8];
        float4 w0 = *(const float4*)(wrow + jc*8);
        float4 w1 = *(const float4*)(wrow + jc*8 + 4);
        float wv[8] = {w0.x,w0.y,w0.z,w0.w, w1.x,w1.y,w1.z,w1.w};
        f16x8 nh, nl;
        #pragma unroll
        for (int j = 0; j < 8; ++j){
          float rold = (float)h8[j] + (float)l8[j] * LO_INV;
          atomicAdd(&vrow[jc*8 + j], rold);
          float rnew = rold - wv[j];
          f16 h = (f16)rnew;
          nh[j] = h;
          nl[j] = (f16)((rnew - (float)h) * LO_SCALE);
          s += rnew * rnew;
        }
        *(f16x8*)&rsh[row][j0 + jc*8] = nh;
        *(f16x8*)&rsl[row][j0 + jc*8] = nl;
      }
      s += __shfl_down(s, 4, 8); s += __shfl_down(s, 2, 8); s += __shfl_down(s, 1, 8);
      if ((tid & 7) == 0) rn_s[row] = s;
    }
    __syncthreads();
  }

  // epilogue: logits = data - resid (fp32), loss += sum(resid^2)
  float lsum = 0.f;
  {
    int c = tid & 31, g = tid >> 5;
    float* optr = out0 + (size_t)b * 524288 + s0;
    #pragma unroll
    for (int dc = 0; dc < 4; ++dc){
      int d0 = g*32 + dc*8;
      f16x8 h8 = *(const f16x8*)&rsh[c][d0];
      f16x8 l8 = *(const f16x8*)&rsl[c][d0];
      #pragma unroll
      for (int j = 0; j < 8; ++j){
        float r = (float)h8[j] + (float)l8[j] * LO_INV;
        lsum += r*r;
        optr[(size_t)(d0+j)*2048 + c] = dptr[(size_t)(d0+j)*2048 + c] - r;
      }
    }
  }
  #pragma unroll
  for (int o = 32; o > 0; o >>= 1) lsum += __shfl_down(lsum, o, 64);
  if ((tid & 63) == 0) atomicAdd(loss_acc, lsum);
}

// ---------- EMA stats epilogue ----------
__global__ __launch_bounds__(256) void stats_kernel(
    const float* __restrict__ Ni, const float* __restrict__ mi,
    const float* __restrict__ counts, const float* __restrict__ vec,
    const float* __restrict__ loss_acc,
    float* __restrict__ outN, float* __restrict__ outM, float* __restrict__ outW,
    float* __restrict__ outLoss){
  size_t e = (size_t)blockIdx.x * 256 + threadIdx.x;
  if (e >= 2097152ull) return;
  int qn = (int)(e >> 8);
  float Nn = Ni[qn] * GAMMA_F + counts[qn] * OMG_F;
  float mn = mi[e]  * GAMMA_F + vec[e]    * OMG_F;
  outM[e] = mn;
  outW[e] = mn / fmaxf(Nn, 1e-8f);
  if ((e & 255) == 0) outN[qn] = Nn;
  if (e == 0) outLoss[0] = loss_acc[0] * (1.0f / 8388608.0f);
}

extern "C" void kernel_launch(void* const* d_in, const int* in_sizes, int n_in,
                              void* d_out, int out_size, void* d_ws, size_t ws_size,
                              hipStream_t stream){
  float* out = (float*)d_out;

  // size-keyed input binding
  const float* data = nullptr; const float* codebooks = nullptr;
  const float* Ni = nullptr;   const float* mi = nullptr;
  for (int i = 0; i < n_in; ++i){
    if      (in_sizes[i] == 8388608) data = (const float*)d_in[i];
    else if (in_sizes[i] == 8192)    Ni   = (const float*)d_in[i];
    else if (in_sizes[i] == 2097152){
      if (!codebooks) codebooks = (const float*)d_in[i];
      else            mi        = (const float*)d_in[i];
    }
  }
  if (!data || !codebooks || !Ni || !mi){
    sentinel_kernel<<<1, 64, 0, stream>>>(out, 6666.0f);
    return;
  }

  // ws layout: Whl frags (8,388,608 B) then fp32 scratch (8,453,380 B)
  const size_t ws_need = 8388608ull + sizeof(float)*(8192ull + 8192ull + 2097152ull + 1ull);
  if (ws_size < ws_need){
    sentinel_kernel<<<1, 64, 0, stream>>>(out, 7777.0f);
    return;
  }
  f16*   whl      = (f16*)d_ws;                         // 4,194,304 halfs
  float* wnormb   = (float*)((char*)d_ws + 8388608);    // 8192
  float* counts   = wnormb + 8192;                      // 8192     (zeroed)
  float* vec      = counts + 8192;                      // 2097152  (zeroed)
  float* loss_acc = vec + 2097152;                      // 1        (zeroed)

  // out offsets (fp32, reference return order)
  float* out0 = out;                  // logits  8388608
  float* out1 = out0 + 8388608;       // loss    1
  float* out2 = out1 + 1;             // indices 262144
  float* out3 = out2 + 262144;        // new_N   8192
  float* out4 = out3 + 8192;          // new_m   2097152
  float* out5 = out4 + 2097152;       // new_W   2097152

  hipMemsetAsync(counts, 0, sizeof(float) * (8192 + 2097152 + 1), stream);

  wsplit_kernel<<<dim3(4096), 64, 0, stream>>>(codebooks, whl);
  rownorm_kernel<<<dim3(8192), 64, 0, stream>>>(codebooks, wnormb, 8192);

  rvq_kernel<<<dim3(1024), 256, 0, stream>>>(data, codebooks, whl, wnormb,
                                             counts, vec, loss_acc, out0, out2);

  stats_kernel<<<dim3(8192), 256, 0, stream>>>(Ni, mi, counts, vec, loss_acc,
                                               out3, out4, out5, out1);
}

// Round 7
// 1332.149 us; speedup vs baseline: 3.7570x; 3.7570x over previous
//
#include <hip/hip_runtime.h>
#include <hip/hip_bf16.h>

// RQV residual VQ — MFMA dist + capless code-grouped update (atomic-light).
// Inputs (fp32): data [16,256,2048], codebooks [8,1024,256], N_i [8,1024], m_i [8,1024,256]
// Outputs (fp32 concat): logits, loss, indices, new_N, new_m, new_W
// ws: AH/AL planes 2x16.78MB + whl 8.39MB + wnorm/rnorm + u16 blockhist/rowlist = 42,237,952 B

using f16   = _Float16;
using f16x8 = __attribute__((ext_vector_type(8))) _Float16;
using f32x4 = __attribute__((ext_vector_type(4))) float;

#define GAMMA_F 0.99f
#define OMG_F   0.01f
#define LO_SCALE 1024.0f
#define LO_INV   (1.0f/1024.0f)

__global__ void sentinel_kernel(float* out, float v){
  if (threadIdx.x == 0 && blockIdx.x == 0) out[0] = v;
}

// fragment-plane address for (row, k): planes are [T][kf][lane][8] halves,
// lane = (row&15) + 16*((k&31)>>3), i = k&7, T = row>>4, kf = k>>5.
static __device__ __forceinline__ size_t plane_off(int row, int k){
  int T = row >> 4, rlo = row & 15;
  int kf = k >> 5, kg = (k & 31) >> 3, i = k & 7;
  return ((size_t)(T*8 + kf)*64 + (rlo + (kg << 4)))*8 + i;
}

// ---------- codebook row norms ----------
__global__ __launch_bounds__(64) void rownorm_kernel(const float* __restrict__ X,
                                                     float* __restrict__ out, int rows){
  int r = blockIdx.x;
  if (r >= rows) return;
  int l = threadIdx.x;
  const float* x = X + (size_t)r * 256;
  float s = 0.f;
  #pragma unroll
  for (int i = 0; i < 4; i++){ float v = x[l + i*64]; s += v*v; }
  #pragma unroll
  for (int o = 32; o > 0; o >>= 1) s += __shfl_down(s, o, 64);
  if (l == 0) out[r] = s;
}

// ---------- codebook split into MFMA B-fragment order ----------
__global__ __launch_bounds__(64) void wsplit_kernel(const float* __restrict__ W,
                                                    f16* __restrict__ frag){
  int blk = blockIdx.x;                 // (q*64+ct)*8+kf
  int lane = threadIdx.x;
  int code = (blk >> 3 << 4) + (lane & 15);
  int k0   = (blk & 7)*32 + (lane >> 4)*8;
  const float* src = W + (size_t)code * 256 + k0;
  float4 a = *(const float4*)(src);
  float4 b = *(const float4*)(src + 4);
  float x[8] = {a.x,a.y,a.z,a.w, b.x,b.y,b.z,b.w};
  f16x8 h8, l8;
  #pragma unroll
  for (int i = 0; i < 8; i++){
    f16 h = (f16)x[i];
    h8[i] = h;
    l8[i] = (f16)((x[i] - (float)h) * LO_SCALE);
  }
  f16* dst = frag + (size_t)blk * 1024 + lane*8;
  *(f16x8*)dst         = h8;
  *(f16x8*)(dst + 512) = l8;
}

// ---------- init: data -> fp16 hi/lo fragment planes + rownorm ----------
__global__ __launch_bounds__(256) void init_kernel(const float* __restrict__ data,
                                                   f16* __restrict__ AH, f16* __restrict__ AL,
                                                   float* __restrict__ rnorm){
  __shared__ float rs[32][264];
  __shared__ float nrmp[32][8];
  int blk = blockIdx.x, b = blk >> 6, s0 = (blk & 63) * 32;
  int tid = threadIdx.x, c = tid & 31, g = tid >> 5;
  const float* dptr = data + (size_t)b * 524288 + s0;
  float np_ = 0.f;
  #pragma unroll 8
  for (int dd = 0; dd < 32; ++dd){
    int d = g*32 + dd;
    float x = dptr[(size_t)d * 2048 + c];
    rs[c][d] = x;
    np_ += x*x;
  }
  nrmp[c][g] = np_;
  __syncthreads();
  if (tid < 32){
    float s = 0.f;
    #pragma unroll
    for (int gg = 0; gg < 8; ++gg) s += nrmp[tid][gg];
    rnorm[blk*32 + tid] = s;
  }
  int T0 = blk*2;
  #pragma unroll
  for (int it = 0; it < 4; ++it){
    int v = tid + it*256;
    int lane = v & 63, kf = (v >> 6) & 7, Tl = v >> 9;
    int rl = (lane & 15) + Tl*16;
    int k0 = kf*32 + (lane >> 4)*8;
    f16x8 h8, l8;
    #pragma unroll
    for (int j = 0; j < 8; ++j){
      float x = rs[rl][k0 + j];
      f16 h = (f16)x;
      h8[j] = h;
      l8[j] = (f16)((x - (float)h) * LO_SCALE);
    }
    size_t off = ((size_t)((T0+Tl)*8 + kf)*64 + lane)*8;
    *(f16x8*)(AH + off) = h8;
    *(f16x8*)(AL + off) = l8;
  }
}

// ---------- out4 = mi * gamma (pre-accumulation init) ----------
__global__ __launch_bounds__(256) void out4init_kernel(const float* __restrict__ mi,
                                                       float* __restrict__ out4){
  int e4 = blockIdx.x*256 + threadIdx.x;      // 524288 float4s
  float4 v = ((const float4*)mi)[e4];
  v.x *= GAMMA_F; v.y *= GAMMA_F; v.z *= GAMMA_F; v.w *= GAMMA_F;
  ((float4*)out4)[e4] = v;
}

// ---------- per-stage distance + argmin (r6 structure, indices -> out2q only) ----------
__global__ __launch_bounds__(256, 1) void dist_kernel(
    const f16* __restrict__ AH, const f16* __restrict__ AL,
    const f16* __restrict__ whl, const float* __restrict__ wnorm,
    const float* __restrict__ rnorm, float* __restrict__ out2q, int q)
{
  __shared__ f16 Bs[2][8192];
  const int tid = threadIdx.x;
  const int lane = tid & 63;
  const int w = tid >> 6;
  const int r0 = blockIdx.x * 128;
  const int rlo = lane & 15, kg = lane >> 4;
  const int T0 = (r0 >> 4) + w*2;

  f16x8 aH[2][8], aL[2][8];
  #pragma unroll
  for (int rt = 0; rt < 2; ++rt)
    #pragma unroll
    for (int kf = 0; kf < 8; ++kf){
      size_t off = ((size_t)((T0+rt)*8 + kf)*64 + lane)*8;
      aH[rt][kf] = *(const f16x8*)(AH + off);
      aL[rt][kf] = *(const f16x8*)(AL + off);
    }
  float rn[2][4];
  #pragma unroll
  for (int rt = 0; rt < 2; ++rt)
    #pragma unroll
    for (int i = 0; i < 4; ++i)
      rn[rt][i] = rnorm[(T0+rt)*16 + kg*4 + i];

  const f16* wb = whl + (size_t)q * 64 * 8192;
  const float* wn = wnorm + (q << 10);

  float bestv[8]; int besti[8];
  #pragma unroll
  for (int r8 = 0; r8 < 8; ++r8){ bestv[r8] = 3.4e38f; besti[r8] = 0; }

  {
    const f16* src = wb;
    f16x8 st[4];
    #pragma unroll
    for (int j = 0; j < 4; ++j) st[j] = *(const f16x8*)(src + tid*8 + j*2048);
    #pragma unroll
    for (int j = 0; j < 4; ++j) *(f16x8*)(&Bs[0][0] + tid*8 + j*2048) = st[j];
  }

  for (int ct = 0; ct < 64; ++ct){
    __syncthreads();
    f16x8 nx[4];
    if (ct < 63){
      const f16* src = wb + (size_t)(ct+1) * 8192;
      #pragma unroll
      for (int j = 0; j < 4; ++j) nx[j] = *(const f16x8*)(src + tid*8 + j*2048);
    }
    const f16* bb = &Bs[ct & 1][0];
    f32x4 hh[2], cr[2];
    #pragma unroll
    for (int rt = 0; rt < 2; ++rt){ hh[rt] = (f32x4)0.0f; cr[rt] = (f32x4)0.0f; }
    #pragma unroll
    for (int kf = 0; kf < 8; ++kf){
      f16x8 bh = *(const f16x8*)(bb + kf*1024 + lane*8);
      f16x8 bl = *(const f16x8*)(bb + kf*1024 + 512 + lane*8);
      hh[0] = __builtin_amdgcn_mfma_f32_16x16x32_f16(aH[0][kf], bh, hh[0], 0,0,0);
      cr[0] = __builtin_amdgcn_mfma_f32_16x16x32_f16(aH[0][kf], bl, cr[0], 0,0,0);
      cr[0] = __builtin_amdgcn_mfma_f32_16x16x32_f16(aL[0][kf], bh, cr[0], 0,0,0);
      hh[1] = __builtin_amdgcn_mfma_f32_16x16x32_f16(aH[1][kf], bh, hh[1], 0,0,0);
      cr[1] = __builtin_amdgcn_mfma_f32_16x16x32_f16(aH[1][kf], bl, cr[1], 0,0,0);
      cr[1] = __builtin_amdgcn_mfma_f32_16x16x32_f16(aL[1][kf], bh, cr[1], 0,0,0);
    }
    {
      int code = (ct << 4) + rlo;
      float wnc = wn[code];
      #pragma unroll
      for (int rt = 0; rt < 2; ++rt)
        #pragma unroll
        for (int i = 0; i < 4; ++i){
          float dot = hh[rt][i] + cr[rt][i] * LO_INV;
          float d2 = (rn[rt][i] + wnc) - 2.0f * dot;
          int r8 = rt*4 + i;
          if (d2 < bestv[r8] || (d2 == bestv[r8] && code < besti[r8])){
            bestv[r8] = d2; besti[r8] = code;
          }
        }
    }
    if (ct < 63){
      #pragma unroll
      for (int j = 0; j < 4; ++j) *(f16x8*)(&Bs[(ct+1) & 1][0] + tid*8 + j*2048) = nx[j];
    }
  }

  #pragma unroll
  for (int off = 1; off <= 8; off <<= 1){
    #pragma unroll
    for (int r8 = 0; r8 < 8; ++r8){
      float ov = __shfl_xor(bestv[r8], off, 16);
      int   oi = __shfl_xor(besti[r8], off, 16);
      if (ov < bestv[r8] || (ov == bestv[r8] && oi < besti[r8])){
        bestv[r8] = ov; besti[r8] = oi;
      }
    }
  }
  if (rlo == 0){
    #pragma unroll
    for (int r8 = 0; r8 < 8; ++r8){
      int rt = r8 >> 2, i = r8 & 3;
      int grow = (T0 + rt)*16 + kg*4 + i;
      out2q[grow] = (float)besti[r8];
    }
  }
}

// ---------- pass A: per-block histogram (32 blocks x 1024 rows) ----------
__global__ __launch_bounds__(256) void hist_kernel(const float* __restrict__ out2q,
                                                   unsigned short* __restrict__ blockhist){
  __shared__ int h[1024];
  int tid = threadIdx.x, b = blockIdx.x;
  #pragma unroll
  for (int i = 0; i < 4; ++i) h[tid + 256*i] = 0;
  __syncthreads();
  #pragma unroll
  for (int j = 0; j < 4; ++j){
    int row = b*1024 + tid + 256*j;
    atomicAdd(&h[(int)out2q[row]], 1);
  }
  __syncthreads();
  #pragma unroll
  for (int i = 0; i < 4; ++i)
    blockhist[b*1024 + tid + 256*i] = (unsigned short)h[tid + 256*i];
}

// ---------- pass B: scan -> per-block starts (in place) + new_N ----------
__global__ __launch_bounds__(256) void scan_kernel(unsigned short* __restrict__ blockhist,
                                                   const float* __restrict__ Ni,
                                                   float* __restrict__ out3, int q){
  __shared__ int wtot[4];
  int tid = threadIdx.x, lane = tid & 63, w = tid >> 6;
  ushort4* bh4 = (ushort4*)blockhist;
  int tx=0, ty=0, tz=0, tw=0;
  for (int b = 0; b < 32; ++b){
    ushort4 h = bh4[b*256 + tid];
    tx += h.x; ty += h.y; tz += h.z; tw += h.w;
  }
  int s = tx + ty + tz + tw;
  int v = s;
  #pragma unroll
  for (int d = 1; d < 64; d <<= 1){
    int o = __shfl_up(v, d, 64);
    if (lane >= d) v += o;
  }
  if (lane == 63) wtot[w] = v;
  __syncthreads();
  int woff = 0;
  #pragma unroll
  for (int ww = 0; ww < 4; ++ww) if (ww < w) woff += wtot[ww];
  int base = woff + v - s;                 // exclusive prefix for code tid*4
  const int qb = q << 10;
  out3[qb + tid*4+0] = Ni[qb + tid*4+0]*GAMMA_F + (float)tx*OMG_F;
  out3[qb + tid*4+1] = Ni[qb + tid*4+1]*GAMMA_F + (float)ty*OMG_F;
  out3[qb + tid*4+2] = Ni[qb + tid*4+2]*GAMMA_F + (float)tz*OMG_F;
  out3[qb + tid*4+3] = Ni[qb + tid*4+3]*GAMMA_F + (float)tw*OMG_F;
  int r0 = base, r1 = base + tx, r2 = r1 + ty, r3 = r2 + tz;
  for (int b = 0; b < 32; ++b){
    ushort4 h = bh4[b*256 + tid];
    ushort4 st; st.x = (unsigned short)r0; st.y = (unsigned short)r1;
    st.z = (unsigned short)r2; st.w = (unsigned short)r3;
    bh4[b*256 + tid] = st;
    r0 += h.x; r1 += h.y; r2 += h.z; r3 += h.w;
  }
}

// ---------- pass C: scatter rows into code-grouped rowlist ----------
__global__ __launch_bounds__(256) void scatter_kernel(const float* __restrict__ out2q,
                                                      const unsigned short* __restrict__ blockhist,
                                                      unsigned short* __restrict__ rowlist){
  __shared__ int cur[1024];
  int tid = threadIdx.x, b = blockIdx.x;
  #pragma unroll
  for (int i = 0; i < 4; ++i) cur[tid + 256*i] = blockhist[b*1024 + tid + 256*i];
  __syncthreads();
  #pragma unroll
  for (int j = 0; j < 4; ++j){
    int row = b*1024 + tid + 256*j;
    int c = (int)out2q[row];
    int pos = atomicAdd(&cur[c], 1);
    rowlist[pos] = (unsigned short)row;
  }
}

// ---------- pass D: balanced update, run-accumulated vec into out4 ----------
__global__ __launch_bounds__(256) void update_kernel(
    f16* __restrict__ AH, f16* __restrict__ AL,
    const unsigned short* __restrict__ rowlist, const float* __restrict__ out2q,
    const float* __restrict__ codebooks, float* __restrict__ out4,
    float* __restrict__ rnorm, int q)
{
  __shared__ float nrm[4][64];
  __shared__ int rows_s[64];
  __shared__ int codes_s[64];
  const int tid = threadIdx.x, lane = tid & 63, w = tid >> 6;
  const int s0 = blockIdx.x * 64;
  if (tid < 64){
    int row = rowlist[s0 + tid];
    rows_s[tid] = row;
    codes_s[tid] = (int)out2q[row];
  }
  __syncthreads();
  int prev = -1; float runsum = 0.f, Wk = 0.f;
  for (int s = 0; s < 64; ++s){
    int row = rows_s[s], code = codes_s[s];
    if (code != prev){
      if (prev >= 0)
        atomicAdd(&out4[(((size_t)q << 10) + prev)*256 + tid], runsum * OMG_F);
      runsum = 0.f;
      Wk = codebooks[(((size_t)q << 10) + code)*256 + tid];
      prev = code;
    }
    size_t off = plane_off(row, tid);
    float rold = (float)AH[off] + (float)AL[off] * LO_INV;
    runsum += rold;
    float rnew = rold - Wk;
    f16 h = (f16)rnew;
    AH[off] = h;
    AL[off] = (f16)((rnew - (float)h) * LO_SCALE);
    float p = rnew * rnew;
    #pragma unroll
    for (int o = 32; o > 0; o >>= 1) p += __shfl_down(p, o, 64);
    if (lane == 0) nrm[w][s] = p;
  }
  atomicAdd(&out4[(((size_t)q << 10) + prev)*256 + tid], runsum * OMG_F);
  __syncthreads();
  if (tid < 64)
    rnorm[rows_s[tid]] = nrm[0][tid] + nrm[1][tid] + nrm[2][tid] + nrm[3][tid];
}

// ---------- epilogue: logits = data - resid, loss ----------
__global__ __launch_bounds__(256) void logits_loss_kernel(
    const float* __restrict__ data, const f16* __restrict__ AH, const f16* __restrict__ AL,
    float* __restrict__ out0, float* __restrict__ out1)
{
  __shared__ float rs[32][264];
  int blk = blockIdx.x, b = blk >> 6, s0 = (blk & 63) * 32;
  int tid = threadIdx.x;
  int T0 = blk*2;
  #pragma unroll
  for (int it = 0; it < 4; ++it){
    int v = tid + it*256;
    int lane = v & 63, kf = (v >> 6) & 7, Tl = v >> 9;
    int rl = (lane & 15) + Tl*16;
    int k0 = kf*32 + (lane >> 4)*8;
    size_t off = ((size_t)((T0+Tl)*8 + kf)*64 + lane)*8;
    f16x8 h8 = *(const f16x8*)(AH + off);
    f16x8 l8 = *(const f16x8*)(AL + off);
    #pragma unroll
    for (int j = 0; j < 8; ++j)
      rs[rl][k0 + j] = (float)h8[j] + (float)l8[j] * LO_INV;
  }
  __syncthreads();
  int c = tid & 31, g = tid >> 5;
  const float* dptr = data + (size_t)b * 524288 + s0;
  float* optr = out0 + (size_t)b * 524288 + s0;
  float lsum = 0.f;
  #pragma unroll 8
  for (int dd = 0; dd < 32; ++dd){
    int d = g*32 + dd;
    float r = rs[c][d];
    lsum += r*r;
    optr[(size_t)d * 2048 + c] = dptr[(size_t)d * 2048 + c] - r;
  }
  #pragma unroll
  for (int o = 32; o > 0; o >>= 1) lsum += __shfl_down(lsum, o, 64);
  if ((tid & 63) == 0) atomicAdd(out1, lsum * (1.0f / 8388608.0f));
}

// ---------- final: new_W = new_m / clip(new_N) ----------
__global__ __launch_bounds__(256) void out5_kernel(const float* __restrict__ out4,
                                                   const float* __restrict__ out3,
                                                   float* __restrict__ out5){
  int e4 = blockIdx.x*256 + threadIdx.x;      // 524288 float4s
  float Nn = fmaxf(out3[e4 >> 6], 1e-8f);
  float4 v = ((const float4*)out4)[e4];
  v.x /= Nn; v.y /= Nn; v.z /= Nn; v.w /= Nn;
  ((float4*)out5)[e4] = v;
}

extern "C" void kernel_launch(void* const* d_in, const int* in_sizes, int n_in,
                              void* d_out, int out_size, void* d_ws, size_t ws_size,
                              hipStream_t stream){
  float* out = (float*)d_out;

  // size-keyed input binding
  const float* data = nullptr; const float* codebooks = nullptr;
  const float* Ni = nullptr;   const float* mi = nullptr;
  for (int i = 0; i < n_in; ++i){
    if      (in_sizes[i] == 8388608) data = (const float*)d_in[i];
    else if (in_sizes[i] == 8192)    Ni   = (const float*)d_in[i];
    else if (in_sizes[i] == 2097152){
      if (!codebooks) codebooks = (const float*)d_in[i];
      else            mi        = (const float*)d_in[i];
    }
  }
  if (!data || !codebooks || !Ni || !mi){
    sentinel_kernel<<<1, 64, 0, stream>>>(out, 6666.0f);
    return;
  }

  // ws layout: AH 16,777,216 | AL 16,777,216 | whl 8,388,608 | wnorm 32,768 |
  //            rnorm 131,072 | blockhist 65,536 | rowlist 65,536  = 42,237,952 B
  const size_t ws_need = 42237952ull;
  if (ws_size < ws_need){
    sentinel_kernel<<<1, 64, 0, stream>>>(out, 7777.0f);
    return;
  }
  f16*   AH     = (f16*)d_ws;
  f16*   AL     = AH + 8388608;
  f16*   whl    = AL + 8388608;
  float* wnormb = (float*)(whl + 4194304);
  float* rnorm  = wnormb + 8192;
  unsigned short* blockhist = (unsigned short*)(rnorm + 32768);
  unsigned short* rowlist   = blockhist + 32768;

  // out offsets (fp32, reference return order)
  float* out0 = out;                  // logits  8388608
  float* out1 = out0 + 8388608;       // loss    1
  float* out2 = out1 + 1;             // indices 262144
  float* out3 = out2 + 262144;        // new_N   8192
  float* out4 = out3 + 8192;          // new_m   2097152
  float* out5 = out4 + 2097152;       // new_W   2097152

  hipMemsetAsync(out1, 0, sizeof(float), stream);

  wsplit_kernel<<<dim3(4096), 64, 0, stream>>>(codebooks, whl);
  rownorm_kernel<<<dim3(8192), 64, 0, stream>>>(codebooks, wnormb, 8192);
  init_kernel<<<dim3(1024), 256, 0, stream>>>(data, AH, AL, rnorm);
  out4init_kernel<<<dim3(2048), 256, 0, stream>>>(mi, out4);

  for (int q = 0; q < 8; ++q){
    float* out2q = out2 + (size_t)q * 32768;
    dist_kernel<<<dim3(256), 256, 0, stream>>>(AH, AL, whl, wnormb, rnorm, out2q, q);
    hist_kernel<<<dim3(32), 256, 0, stream>>>(out2q, blockhist);
    scan_kernel<<<dim3(1), 256, 0, stream>>>(blockhist, Ni, out3, q);
    scatter_kernel<<<dim3(32), 256, 0, stream>>>(out2q, blockhist, rowlist);
    update_kernel<<<dim3(512), 256, 0, stream>>>(AH, AL, rowlist, out2q,
                                                 codebooks, out4, rnorm, q);
  }

  logits_loss_kernel<<<dim3(1024), 256, 0, stream>>>(data, AH, AL, out0, out1);
  out5_kernel<<<dim3(2048), 256, 0, stream>>>(out4, out3, out5);
}

// Round 8
// 867.044 us; speedup vs baseline: 5.7724x; 1.5364x over previous
//
#include <hip/hip_runtime.h>
#include <hip/hip_bf16.h>

// RQV residual VQ — MFMA dist (4-way code-split) + row-major resid planes.
// Inputs (fp32): data [16,256,2048], codebooks [8,1024,256], N_i [8,1024], m_i [8,1024,256]
// Outputs (fp32 concat): logits, loss, indices, new_N, new_m, new_W
// ws: AH/AL row-major planes 2x16.78MB + whl 8.39MB + wnorm/rnorm + blockhist/rowlist
//     + pv/pi partials = 43,122,688 B

using f16   = _Float16;
using f16x4 = __attribute__((ext_vector_type(4))) _Float16;
using f16x8 = __attribute__((ext_vector_type(8))) _Float16;
using f32x4 = __attribute__((ext_vector_type(4))) float;

#define GAMMA_F 0.99f
#define OMG_F   0.01f
#define LO_SCALE 1024.0f
#define LO_INV   (1.0f/1024.0f)

__global__ void sentinel_kernel(float* out, float v){
  if (threadIdx.x == 0 && blockIdx.x == 0) out[0] = v;
}

// ---------- codebook row norms ----------
__global__ __launch_bounds__(64) void rownorm_kernel(const float* __restrict__ X,
                                                     float* __restrict__ out, int rows){
  int r = blockIdx.x;
  if (r >= rows) return;
  int l = threadIdx.x;
  const float* x = X + (size_t)r * 256;
  float s = 0.f;
  #pragma unroll
  for (int i = 0; i < 4; i++){ float v = x[l + i*64]; s += v*v; }
  #pragma unroll
  for (int o = 32; o > 0; o >>= 1) s += __shfl_down(s, o, 64);
  if (l == 0) out[r] = s;
}

// ---------- codebook split into MFMA B-fragment order (unchanged, verified) ----------
__global__ __launch_bounds__(64) void wsplit_kernel(const float* __restrict__ W,
                                                    f16* __restrict__ frag){
  int blk = blockIdx.x;                 // (q*64+ct)*8+kf
  int lane = threadIdx.x;
  int code = (blk >> 3 << 4) + (lane & 15);
  int k0   = (blk & 7)*32 + (lane >> 4)*8;
  const float* src = W + (size_t)code * 256 + k0;
  float4 a = *(const float4*)(src);
  float4 b = *(const float4*)(src + 4);
  float x[8] = {a.x,a.y,a.z,a.w, b.x,b.y,b.z,b.w};
  f16x8 h8, l8;
  #pragma unroll
  for (int i = 0; i < 8; i++){
    f16 h = (f16)x[i];
    h8[i] = h;
    l8[i] = (f16)((x[i] - (float)h) * LO_SCALE);
  }
  f16* dst = frag + (size_t)blk * 1024 + lane*8;
  *(f16x8*)dst         = h8;
  *(f16x8*)(dst + 512) = l8;
}

// ---------- init: data -> ROW-MAJOR fp16 hi/lo planes + rownorm ----------
__global__ __launch_bounds__(256) void init_kernel(const float* __restrict__ data,
                                                   f16* __restrict__ AH, f16* __restrict__ AL,
                                                   float* __restrict__ rnorm){
  __shared__ float rs[32][257];
  __shared__ float nrmp[32][8];
  int blk = blockIdx.x, b = blk >> 6, s0 = (blk & 63) * 32;
  int tid = threadIdx.x, c = tid & 31, g = tid >> 5;
  const float* dptr = data + (size_t)b * 524288 + s0;
  float np_ = 0.f;
  #pragma unroll 8
  for (int dd = 0; dd < 32; ++dd){
    int d = g*32 + dd;
    float x = dptr[(size_t)d * 2048 + c];
    rs[c][d] = x;
    np_ += x*x;
  }
  nrmp[c][g] = np_;
  __syncthreads();
  if (tid < 32){
    float s = 0.f;
    #pragma unroll
    for (int gg = 0; gg < 8; ++gg) s += nrmp[tid][gg];
    rnorm[blk*32 + tid] = s;
  }
  int r0 = blk*32;
  int c2 = tid >> 3, k0 = (tid & 7) * 32;
  #pragma unroll
  for (int jc = 0; jc < 4; ++jc){
    f16x8 h8, l8;
    #pragma unroll
    for (int j = 0; j < 8; ++j){
      float x = rs[c2][k0 + jc*8 + j];
      f16 h = (f16)x;
      h8[j] = h;
      l8[j] = (f16)((x - (float)h) * LO_SCALE);
    }
    size_t off = (size_t)(r0 + c2) * 256 + k0 + jc*8;
    *(f16x8*)(AH + off) = h8;
    *(f16x8*)(AL + off) = l8;
  }
}

// ---------- out4 = mi * gamma ----------
__global__ __launch_bounds__(256) void out4init_kernel(const float* __restrict__ mi,
                                                       float* __restrict__ out4){
  int e4 = blockIdx.x*256 + threadIdx.x;
  float4 v = ((const float4*)mi)[e4];
  v.x *= GAMMA_F; v.y *= GAMMA_F; v.z *= GAMMA_F; v.w *= GAMMA_F;
  ((float4*)out4)[e4] = v;
}

// ---------- dist: 4-way code-split, 2 blocks/CU ----------
__global__ __launch_bounds__(256, 2) void dist_kernel(
    const f16* __restrict__ AH, const f16* __restrict__ AL,
    const f16* __restrict__ whl, const float* __restrict__ wnorm,
    const float* __restrict__ rnorm, float* __restrict__ pv,
    unsigned short* __restrict__ pi, int q)
{
  __shared__ f16 Bs[2][8192];
  const int tid = threadIdx.x;
  const int lane = tid & 63;
  const int w = tid >> 6;
  const int rb = blockIdx.x, cs = blockIdx.y;
  const int rlo = lane & 15, kg = lane >> 4;
  const int T0 = rb*8 + w*2;

  // A fragments from row-major planes: full-line coalesced
  f16x8 aH[2][8], aL[2][8];
  #pragma unroll
  for (int rt = 0; rt < 2; ++rt)
    #pragma unroll
    for (int kf = 0; kf < 8; ++kf){
      size_t off = (size_t)((T0+rt)*16 + rlo) * 256 + kf*32 + kg*8;
      aH[rt][kf] = *(const f16x8*)(AH + off);
      aL[rt][kf] = *(const f16x8*)(AL + off);
    }
  float rn[2][4];
  #pragma unroll
  for (int rt = 0; rt < 2; ++rt)
    #pragma unroll
    for (int i = 0; i < 4; ++i)
      rn[rt][i] = rnorm[(T0+rt)*16 + kg*4 + i];

  const f16* wb = whl + (size_t)q * 64 * 8192;
  const float* wn = wnorm + (q << 10);
  const int ct0 = cs * 16;

  float bestv[8]; int besti[8];
  #pragma unroll
  for (int r8 = 0; r8 < 8; ++r8){ bestv[r8] = 3.4e38f; besti[r8] = 0; }

  {
    const f16* src = wb + (size_t)ct0 * 8192;
    f16x8 st[4];
    #pragma unroll
    for (int j = 0; j < 4; ++j) st[j] = *(const f16x8*)(src + tid*8 + j*2048);
    #pragma unroll
    for (int j = 0; j < 4; ++j) *(f16x8*)(&Bs[0][0] + tid*8 + j*2048) = st[j];
  }

  for (int it = 0; it < 16; ++it){
    int ct = ct0 + it;
    __syncthreads();
    f16x8 nx[4];
    if (it < 15){
      const f16* src = wb + (size_t)(ct+1) * 8192;
      #pragma unroll
      for (int j = 0; j < 4; ++j) nx[j] = *(const f16x8*)(src + tid*8 + j*2048);
    }
    const f16* bb = &Bs[it & 1][0];
    f32x4 hh[2], cr[2];
    #pragma unroll
    for (int rt = 0; rt < 2; ++rt){ hh[rt] = (f32x4)0.0f; cr[rt] = (f32x4)0.0f; }
    #pragma unroll
    for (int kf = 0; kf < 8; ++kf){
      f16x8 bh = *(const f16x8*)(bb + kf*1024 + lane*8);
      f16x8 bl = *(const f16x8*)(bb + kf*1024 + 512 + lane*8);
      hh[0] = __builtin_amdgcn_mfma_f32_16x16x32_f16(aH[0][kf], bh, hh[0], 0,0,0);
      cr[0] = __builtin_amdgcn_mfma_f32_16x16x32_f16(aH[0][kf], bl, cr[0], 0,0,0);
      cr[0] = __builtin_amdgcn_mfma_f32_16x16x32_f16(aL[0][kf], bh, cr[0], 0,0,0);
      hh[1] = __builtin_amdgcn_mfma_f32_16x16x32_f16(aH[1][kf], bh, hh[1], 0,0,0);
      cr[1] = __builtin_amdgcn_mfma_f32_16x16x32_f16(aH[1][kf], bl, cr[1], 0,0,0);
      cr[1] = __builtin_amdgcn_mfma_f32_16x16x32_f16(aL[1][kf], bh, cr[1], 0,0,0);
    }
    {
      int code = (ct << 4) + rlo;
      float wnc = wn[code];
      #pragma unroll
      for (int rt = 0; rt < 2; ++rt)
        #pragma unroll
        for (int i = 0; i < 4; ++i){
          float dot = hh[rt][i] + cr[rt][i] * LO_INV;
          float d2 = (rn[rt][i] + wnc) - 2.0f * dot;
          int r8 = rt*4 + i;
          if (d2 < bestv[r8] || (d2 == bestv[r8] && code < besti[r8])){
            bestv[r8] = d2; besti[r8] = code;
          }
        }
    }
    if (it < 15){
      #pragma unroll
      for (int j = 0; j < 4; ++j) *(f16x8*)(&Bs[(it+1) & 1][0] + tid*8 + j*2048) = nx[j];
    }
  }

  #pragma unroll
  for (int off = 1; off <= 8; off <<= 1){
    #pragma unroll
    for (int r8 = 0; r8 < 8; ++r8){
      float ov = __shfl_xor(bestv[r8], off, 16);
      int   oi = __shfl_xor(besti[r8], off, 16);
      if (ov < bestv[r8] || (ov == bestv[r8] && oi < besti[r8])){
        bestv[r8] = ov; besti[r8] = oi;
      }
    }
  }
  if (rlo == 0){
    #pragma unroll
    for (int r8 = 0; r8 < 8; ++r8){
      int rt = r8 >> 2, i = r8 & 3;
      int grow = (T0 + rt)*16 + kg*4 + i;
      pv[cs*32768 + grow] = bestv[r8];
      pi[cs*32768 + grow] = (unsigned short)besti[r8];
    }
  }
}

// ---------- combine partials + per-block histogram ----------
__global__ __launch_bounds__(256) void combine_kernel(
    const float* __restrict__ pv, const unsigned short* __restrict__ pi,
    float* __restrict__ out2q, unsigned short* __restrict__ blockhist){
  __shared__ int h[1024];
  int tid = threadIdx.x, b = blockIdx.x;
  #pragma unroll
  for (int i = 0; i < 4; ++i) h[tid + 256*i] = 0;
  __syncthreads();
  #pragma unroll
  for (int j = 0; j < 4; ++j){
    int row = b*1024 + tid + 256*j;
    float bv = pv[row]; int bi = pi[row];
    #pragma unroll
    for (int cs = 1; cs < 4; ++cs){
      float v = pv[cs*32768 + row];
      int  ii = pi[cs*32768 + row];
      if (v < bv){ bv = v; bi = ii; }     // strict <: ties keep lower cs = lower code
    }
    out2q[row] = (float)bi;
    atomicAdd(&h[bi], 1);
  }
  __syncthreads();
  #pragma unroll
  for (int i = 0; i < 4; ++i)
    blockhist[b*1024 + tid + 256*i] = (unsigned short)h[tid + 256*i];
}

// ---------- scan -> per-block starts (in place) + new_N ----------
__global__ __launch_bounds__(256) void scan_kernel(unsigned short* __restrict__ blockhist,
                                                   const float* __restrict__ Ni,
                                                   float* __restrict__ out3, int q){
  __shared__ int wtot[4];
  int tid = threadIdx.x, lane = tid & 63, w = tid >> 6;
  ushort4* bh4 = (ushort4*)blockhist;
  int tx=0, ty=0, tz=0, tw=0;
  for (int b = 0; b < 32; ++b){
    ushort4 h = bh4[b*256 + tid];
    tx += h.x; ty += h.y; tz += h.z; tw += h.w;
  }
  int s = tx + ty + tz + tw;
  int v = s;
  #pragma unroll
  for (int d = 1; d < 64; d <<= 1){
    int o = __shfl_up(v, d, 64);
    if (lane >= d) v += o;
  }
  if (lane == 63) wtot[w] = v;
  __syncthreads();
  int woff = 0;
  #pragma unroll
  for (int ww = 0; ww < 4; ++ww) if (ww < w) woff += wtot[ww];
  int base = woff + v - s;
  const int qb = q << 10;
  out3[qb + tid*4+0] = Ni[qb + tid*4+0]*GAMMA_F + (float)tx*OMG_F;
  out3[qb + tid*4+1] = Ni[qb + tid*4+1]*GAMMA_F + (float)ty*OMG_F;
  out3[qb + tid*4+2] = Ni[qb + tid*4+2]*GAMMA_F + (float)tz*OMG_F;
  out3[qb + tid*4+3] = Ni[qb + tid*4+3]*GAMMA_F + (float)tw*OMG_F;
  int r0 = base, r1 = base + tx, r2 = r1 + ty, r3 = r2 + tz;
  for (int b = 0; b < 32; ++b){
    ushort4 h = bh4[b*256 + tid];
    ushort4 st; st.x = (unsigned short)r0; st.y = (unsigned short)r1;
    st.z = (unsigned short)r2; st.w = (unsigned short)r3;
    bh4[b*256 + tid] = st;
    r0 += h.x; r1 += h.y; r2 += h.z; r3 += h.w;
  }
}

// ---------- scatter rows into code-grouped rowlist ----------
__global__ __launch_bounds__(256) void scatter_kernel(const float* __restrict__ out2q,
                                                      const unsigned short* __restrict__ blockhist,
                                                      unsigned short* __restrict__ rowlist){
  __shared__ int cur[1024];
  int tid = threadIdx.x, b = blockIdx.x;
  #pragma unroll
  for (int i = 0; i < 4; ++i) cur[tid + 256*i] = blockhist[b*1024 + tid + 256*i];
  __syncthreads();
  #pragma unroll
  for (int j = 0; j < 4; ++j){
    int row = b*1024 + tid + 256*j;
    int c = (int)out2q[row];
    int pos = atomicAdd(&cur[c], 1);
    rowlist[pos] = (unsigned short)row;
  }
}

// ---------- update: 1-wave blocks, 16 code-grouped slots, row-major contiguous ----------
__global__ __launch_bounds__(64) void update_kernel(
    f16* __restrict__ AH, f16* __restrict__ AL,
    const unsigned short* __restrict__ rowlist, const float* __restrict__ out2q,
    const float* __restrict__ codebooks, float* __restrict__ out4,
    float* __restrict__ rnorm, int q)
{
  const int lane = threadIdx.x;
  const int s0 = blockIdx.x * 16;
  int myrow = 0, mycode = 0;
  if (lane < 16){
    myrow = rowlist[s0 + lane];
    mycode = (int)out2q[myrow];
  }
  float vs[4] = {0.f, 0.f, 0.f, 0.f};
  float Wk[4] = {0.f, 0.f, 0.f, 0.f};
  int prev = -1;
  for (int s = 0; s < 16; ++s){
    int row  = __shfl(myrow, s, 64);
    int code = __shfl(mycode, s, 64);
    if (code != prev){
      if (prev >= 0){
        float* dst = out4 + (((size_t)q << 10) + prev)*256 + lane*4;
        #pragma unroll
        for (int t = 0; t < 4; ++t) atomicAdd(dst + t, vs[t] * OMG_F);
      }
      float4 wv = *(const float4*)&codebooks[(((size_t)q << 10) + code)*256 + lane*4];
      Wk[0] = wv.x; Wk[1] = wv.y; Wk[2] = wv.z; Wk[3] = wv.w;
      vs[0] = vs[1] = vs[2] = vs[3] = 0.f;
      prev = code;
    }
    size_t base = (size_t)row * 256 + lane*4;
    f16x4 h4 = *(const f16x4*)(AH + base);
    f16x4 l4 = *(const f16x4*)(AL + base);
    f16x4 nh, nl;
    float p = 0.f;
    #pragma unroll
    for (int t = 0; t < 4; ++t){
      float rj = (float)h4[t] + (float)l4[t] * LO_INV;
      vs[t] += rj;
      float rn_ = rj - Wk[t];
      f16 hh = (f16)rn_;
      nh[t] = hh;
      nl[t] = (f16)((rn_ - (float)hh) * LO_SCALE);
      p += rn_ * rn_;
    }
    *(f16x4*)(AH + base) = nh;
    *(f16x4*)(AL + base) = nl;
    #pragma unroll
    for (int o = 32; o > 0; o >>= 1) p += __shfl_down(p, o, 64);
    if (lane == 0) rnorm[row] = p;
  }
  if (prev >= 0){
    float* dst = out4 + (((size_t)q << 10) + prev)*256 + lane*4;
    #pragma unroll
    for (int t = 0; t < 4; ++t) atomicAdd(dst + t, vs[t] * OMG_F);
  }
}

// ---------- epilogue: logits = data - resid, loss ----------
__global__ __launch_bounds__(256) void logits_loss_kernel(
    const float* __restrict__ data, const f16* __restrict__ AH, const f16* __restrict__ AL,
    float* __restrict__ out0, float* __restrict__ out1)
{
  __shared__ float rs[32][257];
  int blk = blockIdx.x, b = blk >> 6, s0 = (blk & 63) * 32;
  int tid = threadIdx.x;
  int r0 = blk*32;
  int c2 = tid >> 3, k0 = (tid & 7) * 32;
  #pragma unroll
  for (int jc = 0; jc < 4; ++jc){
    size_t off = (size_t)(r0 + c2) * 256 + k0 + jc*8;
    f16x8 h8 = *(const f16x8*)(AH + off);
    f16x8 l8 = *(const f16x8*)(AL + off);
    #pragma unroll
    for (int j = 0; j < 8; ++j)
      rs[c2][k0 + jc*8 + j] = (float)h8[j] + (float)l8[j] * LO_INV;
  }
  __syncthreads();
  int c = tid & 31, g = tid >> 5;
  const float* dptr = data + (size_t)b * 524288 + s0;
  float* optr = out0 + (size_t)b * 524288 + s0;
  float lsum = 0.f;
  #pragma unroll 8
  for (int dd = 0; dd < 32; ++dd){
    int d = g*32 + dd;
    float r = rs[c][d];
    lsum += r*r;
    optr[(size_t)d * 2048 + c] = dptr[(size_t)d * 2048 + c] - r;
  }
  #pragma unroll
  for (int o = 32; o > 0; o >>= 1) lsum += __shfl_down(lsum, o, 64);
  if ((tid & 63) == 0) atomicAdd(out1, lsum * (1.0f / 8388608.0f));
}

// ---------- final: new_W = new_m / clip(new_N) ----------
__global__ __launch_bounds__(256) void out5_kernel(const float* __restrict__ out4,
                                                   const float* __restrict__ out3,
                                                   float* __restrict__ out5){
  int e4 = blockIdx.x*256 + threadIdx.x;
  float Nn = fmaxf(out3[e4 >> 6], 1e-8f);
  float4 v = ((const float4*)out4)[e4];
  v.x /= Nn; v.y /= Nn; v.z /= Nn; v.w /= Nn;
  ((float4*)out5)[e4] = v;
}

extern "C" void kernel_launch(void* const* d_in, const int* in_sizes, int n_in,
                              void* d_out, int out_size, void* d_ws, size_t ws_size,
                              hipStream_t stream){
  float* out = (float*)d_out;

  // size-keyed input binding
  const float* data = nullptr; const float* codebooks = nullptr;
  const float* Ni = nullptr;   const float* mi = nullptr;
  for (int i = 0; i < n_in; ++i){
    if      (in_sizes[i] == 8388608) data = (const float*)d_in[i];
    else if (in_sizes[i] == 8192)    Ni   = (const float*)d_in[i];
    else if (in_sizes[i] == 2097152){
      if (!codebooks) codebooks = (const float*)d_in[i];
      else            mi        = (const float*)d_in[i];
    }
  }
  if (!data || !codebooks || !Ni || !mi){
    sentinel_kernel<<<1, 64, 0, stream>>>(out, 6666.0f);
    return;
  }

  // ws layout (bytes):
  // AH 16,777,216 | AL 16,777,216 | whl 8,388,608 | wnorm 32,768 | rnorm 131,072 |
  // blockhist 65,536 | rowlist 65,536 | pv 524,288 | pi 262,144  = 43,122,688
  const size_t ws_need = 43122688ull;
  if (ws_size < ws_need){
    sentinel_kernel<<<1, 64, 0, stream>>>(out, 7777.0f);
    return;
  }
  f16*   AH     = (f16*)d_ws;
  f16*   AL     = AH + 8388608;
  f16*   whl    = AL + 8388608;
  float* wnormb = (float*)(whl + 4194304);
  float* rnorm  = wnormb + 8192;
  unsigned short* blockhist = (unsigned short*)(rnorm + 32768);
  unsigned short* rowlist   = blockhist + 32768;
  float* pv     = (float*)(rowlist + 32768);
  unsigned short* pi = (unsigned short*)(pv + 131072);

  // out offsets (fp32, reference return order)
  float* out0 = out;                  // logits  8388608
  float* out1 = out0 + 8388608;       // loss    1
  float* out2 = out1 + 1;             // indices 262144
  float* out3 = out2 + 262144;        // new_N   8192
  float* out4 = out3 + 8192;          // new_m   2097152
  float* out5 = out4 + 2097152;       // new_W   2097152

  hipMemsetAsync(out1, 0, sizeof(float), stream);

  wsplit_kernel<<<dim3(4096), 64, 0, stream>>>(codebooks, whl);
  rownorm_kernel<<<dim3(8192), 64, 0, stream>>>(codebooks, wnormb, 8192);
  init_kernel<<<dim3(1024), 256, 0, stream>>>(data, AH, AL, rnorm);
  out4init_kernel<<<dim3(2048), 256, 0, stream>>>(mi, out4);

  for (int q = 0; q < 8; ++q){
    float* out2q = out2 + (size_t)q * 32768;
    dist_kernel<<<dim3(256, 4), 256, 0, stream>>>(AH, AL, whl, wnormb, rnorm, pv, pi, q);
    combine_kernel<<<dim3(32), 256, 0, stream>>>(pv, pi, out2q, blockhist);
    scan_kernel<<<dim3(1), 256, 0, stream>>>(blockhist, Ni, out3, q);
    scatter_kernel<<<dim3(32), 256, 0, stream>>>(out2q, blockhist, rowlist);
    update_kernel<<<dim3(2048), 64, 0, stream>>>(AH, AL, rowlist, out2q,
                                                 codebooks, out4, rnorm, q);
  }

  logits_loss_kernel<<<dim3(1024), 256, 0, stream>>>(data, AH, AL, out0, out1);
  out5_kernel<<<dim3(2048), 256, 0, stream>>>(out4, out3, out5);
}